// Round 4
// baseline (530.877 us; speedup 1.0000x reference)
//
#include <hip/hip_runtime.h>
#include <hip/hip_bf16.h>
#include <cstdint>
#include <cstddef>

#define T_TOK 8192
#define H_DIM 768
#define I_DIM 1024
#define N_EXP 5
#define MAXTILE 136

#define NGU (MAXTILE * 16)   // 2176 gate+up items (tile, 64-I-col block)
#define NDN (MAXTILE * 6)    // 816 down items (tile, 128-H-col block)
#define NCB 768              // combine items (8192 elems each)
#define QPRE 1024            // gu items before interleave starts (tiles 0..63)
#define QG 72                // interleave groups: {16 gu of tile 64+g, 6 down of tile g}
#define QMID (QG * 22)       // 1584
#define QD2 384              // trailing down items (tiles 72..135)

typedef short v8s __attribute__((ext_vector_type(8)));
typedef float v4f __attribute__((ext_vector_type(4)));

static __device__ __forceinline__ unsigned short f2bf(float f) {
    union { float f; unsigned int u; } v; v.f = f;
    unsigned int u = v.u;
    unsigned int r = (u + 0x7fffu + ((u >> 16) & 1u)) >> 16;
    return (unsigned short)r;
}
static __device__ __forceinline__ float bf2f(unsigned short s) {
    union { unsigned int u; float f; } v; v.u = ((unsigned int)s) << 16; return v.f;
}

// async 16B global->LDS (wave-uniform LDS base + lane*16)
static __device__ __forceinline__ void async16(const unsigned short* g, unsigned short* l) {
    __builtin_amdgcn_global_load_lds(
        (const __attribute__((address_space(1))) unsigned int*)g,
        (__attribute__((address_space(3))) unsigned int*)l, 16, 0, 0);
}

// ---- prep: 64x64-tile weight transposes (z<15) + router/x->bf16, 4 tok/wave (z>=15) ----
__global__ void k_prep(const float* __restrict__ gw, const float* __restrict__ uw,
                       const float* __restrict__ dw,
                       unsigned short* __restrict__ wbt, unsigned short* __restrict__ dbt,
                       const float* __restrict__ x, const float* __restrict__ rw,
                       const float* __restrict__ rb, unsigned short* __restrict__ xb,
                       int* __restrict__ top2e, float2* __restrict__ top2w) {
    const int z = blockIdx.z;
    const int tid = threadIdx.x;
    if (z < 3 * N_EXP) {
        __shared__ float tile[64][65];
        const int lrow = tid >> 4;
        const int lcol = (tid & 15) * 4;
        const int ocol = tid >> 2;
        const int seg = tid & 3;
        if (z < 2 * N_EXP) {
            if (blockIdx.y >= H_DIM / 64) return;
            const int e = z % N_EXP;
            const int isUp = z >= N_EXP;
            const float* src = (isUp ? uw : gw) + (size_t)e * H_DIM * I_DIM;
            const int c0 = blockIdx.x * 64, r0 = blockIdx.y * 64;
#pragma unroll
            for (int i = 0; i < 4; i++) {
                float4 v = *(const float4*)(src + (size_t)(r0 + i * 16 + lrow) * I_DIM + c0 + lcol);
                tile[i * 16 + lrow][lcol + 0] = v.x; tile[i * 16 + lrow][lcol + 1] = v.y;
                tile[i * 16 + lrow][lcol + 2] = v.z; tile[i * 16 + lrow][lcol + 3] = v.w;
            }
            __syncthreads();
            const int c = c0 + ocol;
            const int orow = (c >> 4) * 32 + (c & 15) + (isUp ? 16 : 0);
            unsigned short* dst = wbt + ((size_t)e * 2 * I_DIM + orow) * H_DIM + r0 + seg * 16;
#pragma unroll
            for (int q = 0; q < 4; q++) {
                ushort4 o;
                o.x = f2bf(tile[seg * 16 + q * 4 + 0][ocol]);
                o.y = f2bf(tile[seg * 16 + q * 4 + 1][ocol]);
                o.z = f2bf(tile[seg * 16 + q * 4 + 2][ocol]);
                o.w = f2bf(tile[seg * 16 + q * 4 + 3][ocol]);
                *(ushort4*)(dst + q * 4) = o;
            }
        } else {
            if (blockIdx.x >= H_DIM / 64) return;
            const int e = z - 2 * N_EXP;
            const float* src = dw + (size_t)e * I_DIM * H_DIM;
            unsigned short* dstb = dbt + (size_t)e * I_DIM * H_DIM;
            const int c0 = blockIdx.x * 64, r0 = blockIdx.y * 64;
#pragma unroll
            for (int i = 0; i < 4; i++) {
                float4 v = *(const float4*)(src + (size_t)(r0 + i * 16 + lrow) * H_DIM + c0 + lcol);
                tile[i * 16 + lrow][lcol + 0] = v.x; tile[i * 16 + lrow][lcol + 1] = v.y;
                tile[i * 16 + lrow][lcol + 2] = v.z; tile[i * 16 + lrow][lcol + 3] = v.w;
            }
            __syncthreads();
            const int c = c0 + ocol;
            unsigned short* dst = dstb + (size_t)c * I_DIM + r0 + seg * 16;
#pragma unroll
            for (int q = 0; q < 4; q++) {
                ushort4 o;
                o.x = f2bf(tile[seg * 16 + q * 4 + 0][ocol]);
                o.y = f2bf(tile[seg * 16 + q * 4 + 1][ocol]);
                o.z = f2bf(tile[seg * 16 + q * 4 + 2][ocol]);
                o.w = f2bf(tile[seg * 16 + q * 4 + 3][ocol]);
                *(ushort4*)(dst + q * 4) = o;
            }
        }
    } else {
        const int wave = tid >> 6, lane = tid & 63;
        const int b = (z - 3 * N_EXP) * 256 + blockIdx.y * 16 + blockIdx.x;
        const int t0 = b * 16 + wave * 4;
        float acc[4][N_EXP];
#pragma unroll
        for (int i = 0; i < 4; i++)
#pragma unroll
            for (int e = 0; e < N_EXP; e++) acc[i][e] = 0.f;
#pragma unroll
        for (int j = 0; j < H_DIM / 256; j++) {
            const int idx = j * 256 + lane * 4;
            float4 xv[4];
#pragma unroll
            for (int i = 0; i < 4; i++) {
                xv[i] = *(const float4*)(x + (size_t)(t0 + i) * H_DIM + idx);
                ushort4 o;
                o.x = f2bf(xv[i].x); o.y = f2bf(xv[i].y); o.z = f2bf(xv[i].z); o.w = f2bf(xv[i].w);
                *(ushort4*)(xb + (size_t)(t0 + i) * H_DIM + idx) = o;
            }
#pragma unroll
            for (int e = 0; e < N_EXP; e++) {
                float4 wv = *(const float4*)(rw + e * H_DIM + idx);
#pragma unroll
                for (int i = 0; i < 4; i++)
                    acc[i][e] += xv[i].x * wv.x + xv[i].y * wv.y + xv[i].z * wv.z + xv[i].w * wv.w;
            }
        }
#pragma unroll
        for (int s = 32; s > 0; s >>= 1) {
#pragma unroll
            for (int i = 0; i < 4; i++)
#pragma unroll
                for (int e = 0; e < N_EXP; e++) acc[i][e] += __shfl_down(acc[i][e], s);
        }
        if (lane == 0) {
#pragma unroll
            for (int i = 0; i < 4; i++) {
                float l[N_EXP];
#pragma unroll
                for (int e = 0; e < N_EXP; e++) l[e] = acc[i][e] + rb[e];
                int i1 = 0;
#pragma unroll
                for (int e = 1; e < N_EXP; e++) if (l[e] > l[i1]) i1 = e;
                int i2 = (i1 == 0) ? 1 : 0;
#pragma unroll
                for (int e = 0; e < N_EXP; e++) if (e != i1 && l[e] > l[i2]) i2 = e;
                float w1 = 1.f / (1.f + __expf(l[i2] - l[i1]));
                top2e[t0 + i] = i1 | (i2 << 8);
                top2w[t0 + i] = make_float2(w1, 1.f - w1);
            }
        }
    }
}

// ---- router phase B: list build + (last block) tile-list build ----
__global__ void k_router_b(const int* __restrict__ top2e, const float2* __restrict__ top2w,
                           int* __restrict__ cnt, int* __restrict__ tokslot,
                           float* __restrict__ pweight, int* __restrict__ done,
                           int4* __restrict__ tiles) {
    __shared__ int lcnt[N_EXP], lbase[N_EXP];
    const int tid = threadIdx.x;
    if (tid < N_EXP) lcnt[tid] = 0;
    __syncthreads();
    const int t = blockIdx.x * 256 + tid;
    const int pe = top2e[t];
    const float2 wv = top2w[t];
    const int e1 = pe & 0xff, e2 = pe >> 8;
    const int s1 = atomicAdd(&lcnt[e1], 1);
    const int s2 = atomicAdd(&lcnt[e2], 1);
    __syncthreads();
    if (tid < N_EXP) lbase[tid] = atomicAdd(&cnt[tid], lcnt[tid]);
    __syncthreads();
    const int p1 = lbase[e1] + s1;
    tokslot[e1 * T_TOK + p1] = t; pweight[e1 * T_TOK + p1] = wv.x;
    const int p2 = lbase[e2] + s2;
    tokslot[e2 * T_TOK + p2] = t | (1 << 16); pweight[e2 * T_TOK + p2] = wv.y;
    __syncthreads();
    if (tid == 0) {
        __threadfence();
        if (atomicAdd(done, 1) == (int)gridDim.x - 1) {
            int c[N_EXP], off = 0, idx = 0;
            for (int e = 0; e < N_EXP; e++) c[e] = atomicAdd(&cnt[e], 0);
            for (int e = 0; e < N_EXP; e++) {
                for (int m0 = 0; m0 < c[e]; m0 += 128)
                    tiles[idx++] = make_int4(e, m0, off, c[e]);
                off += c[e];
            }
            for (; idx < MAXTILE; idx++) tiles[idx] = make_int4(-1, 0, 0, 0);
        }
    }
}

// ---- fused mega kernel: queue-driven gateup -> down -> combine ----
// Block grabs a ticket; ticket ranges map to roles. Queue order guarantees a
// tile's gateup items are grabbed >=1408 tickets before its down items
// (producers resident/finished before consumers arrive -> bounded spin, no
// deadlock). gucnt[tile] counts finished gateup items (target 16); dncnt
// counts finished down items (target NDN). AGENT-scope release adds publish;
// relaxed AGENT polls + acquire fence consume (cross-XCD safe).
__launch_bounds__(256, 4)
__global__ void k_mega(const unsigned short* __restrict__ xb,
                       const unsigned short* __restrict__ wbt,
                       const unsigned short* __restrict__ dbt,
                       const int4* __restrict__ tiles,
                       const int* __restrict__ tokslot,
                       const float* __restrict__ pweight,
                       unsigned short* __restrict__ hbuf,
                       unsigned short* __restrict__ ybuf,
                       float* __restrict__ out,
                       int* __restrict__ qhead,
                       int* __restrict__ gucnt,
                       int* __restrict__ dncnt) {
    __shared__ __align__(16) unsigned short ldsA[128 * 64];
    __shared__ __align__(16) unsigned short ldsB[128 * 64];
    __shared__ int tokLds[128];
    __shared__ float pwLds[128];
    __shared__ int widxS;

    const int tid = threadIdx.x;
    if (tid == 0)
        widxS = __hip_atomic_fetch_add(qhead, 1, __ATOMIC_RELAXED, __HIP_MEMORY_SCOPE_AGENT);
    __syncthreads();
    const int widx = widxS;

    int role, item;
    if (widx < QPRE) { role = 0; item = widx; }
    else if (widx < QPRE + QMID) {
        const int w2 = widx - QPRE, g = w2 / 22, r = w2 % 22;
        if (r < 16) { role = 0; item = QPRE + g * 16 + r; }
        else        { role = 1; item = g * 6 + (r - 16); }
    } else if (widx < QPRE + QMID + QD2) {
        role = 1; item = QG * 6 + (widx - (QPRE + QMID));
    } else {
        role = 2; item = widx - (QPRE + QMID + QD2);
    }

    const int lane = tid & 63;
    const int wave = tid >> 6;
    const int fm = lane & 15, quad = lane >> 4;
    const int prow = lane >> 3;
    const int pc = lane & 7;
    const int lc8 = (pc ^ prow) * 8;

    if (role == 0) {
        // ---------------- gate+up item: tile bx, I-col block by ----------------
        const int bx = item >> 4, by = item & 15;
        const int4 td = tiles[bx];
        const int e = td.x;
        if (e >= 0) {
            const int m0 = td.y, offe = td.z, cn = td.w;
            const int n0 = by * 64;
            if (tid < 128) {
                int gr = m0 + tid;
                int tk = 0; float pw = 0.f;
                if (gr < cn) { tk = tokslot[e * T_TOK + gr] & 0xFFFF; pw = pweight[e * T_TOK + gr]; }
                tokLds[tid] = tk; pwLds[tid] = pw;
            }
            __syncthreads();

            unsigned aOff[4];
#pragma unroll
            for (int c = 0; c < 4; c++)
                aOff[c] = (unsigned)tokLds[c * 32 + wave * 8 + prow] * H_DIM;
            const unsigned short* aBase = xb + lc8;
            const unsigned short* bBase =
                wbt + ((size_t)e * 2 * I_DIM + n0 * 2 + wave * 8 + prow) * H_DIM + lc8;
            unsigned short* ldsAW = ldsA + wave * 8 * 64;
            unsigned short* ldsBW = ldsB + wave * 8 * 64;

            const int wm = (wave & 1) * 64, wnw = wave >> 1;

            v4f acc[4][4];
#pragma unroll
            for (int i = 0; i < 4; i++)
#pragma unroll
                for (int j = 0; j < 4; j++) acc[i][j] = (v4f)0.f;

            for (int kb = 0; kb < H_DIM / 64; kb++) {
                const int k0 = kb * 64;
#pragma unroll
                for (int c = 0; c < 4; c++)
                    async16(aBase + aOff[c] + k0, ldsAW + c * 32 * 64);
#pragma unroll
                for (int c = 0; c < 4; c++)
                    async16(bBase + (size_t)c * 32 * H_DIM + k0, ldsBW + c * 32 * 64);
                __syncthreads();
#pragma unroll
                for (int ks = 0; ks < 2; ks++) {
                    const int pq = ((ks * 4 + quad) ^ (fm & 7)) * 8;
                    v8s aF[4], bF[4];
#pragma unroll
                    for (int im = 0; im < 4; im++)
                        aF[im] = *(const v8s*)&ldsA[(wm + im * 16 + fm) * 64 + pq];
#pragma unroll
                    for (int in = 0; in < 4; in++)
                        bF[in] = *(const v8s*)&ldsB[(wnw * 64 + in * 16 + fm) * 64 + pq];
#pragma unroll
                    for (int im = 0; im < 4; im++)
#pragma unroll
                        for (int in = 0; in < 4; in++)
                            acc[im][in] = __builtin_amdgcn_mfma_f32_16x16x32_bf16(aF[im], bF[in], acc[im][in], 0, 0, 0);
                }
                __syncthreads();
            }

#pragma unroll
            for (int im = 0; im < 4; im++) {
#pragma unroll
                for (int reg = 0; reg < 4; reg++) {
                    int lr = wm + im * 16 + quad * 4 + reg;
                    int gr = m0 + lr;
                    if (gr < cn) {
                        float pw = pwLds[lr];
                        size_t base = (size_t)(offe + gr) * I_DIM + n0 + wnw * 32 + fm;
#pragma unroll
                        for (int j = 0; j < 2; j++) {
                            float g = acc[im][2 * j][reg];
                            float u = acc[im][2 * j + 1][reg];
                            float s = g / (1.f + __expf(-g));
                            hbuf[base + j * 16] = f2bf(s * u * pw);
                        }
                    }
                }
            }
        }
        __syncthreads();
        if (tid == 0)
            __hip_atomic_fetch_add(&gucnt[bx], 1, __ATOMIC_RELEASE, __HIP_MEMORY_SCOPE_AGENT);
    } else if (role == 1) {
        // ---------------- down item: tile bx, H-col block by ----------------
        const int bx = item / 6, by = item % 6;
        if (tid == 0) {
            while (__hip_atomic_load(&gucnt[bx], __ATOMIC_RELAXED, __HIP_MEMORY_SCOPE_AGENT) < 16)
                __builtin_amdgcn_s_sleep(16);
        }
        __syncthreads();
        __builtin_amdgcn_fence(__ATOMIC_ACQUIRE, "agent");

        const int4 td = tiles[bx];
        const int e = td.x;
        if (e >= 0) {
            const int m0 = td.y, offe = td.z, cn = td.w;
            const int n0 = by * 128;
            if (tid < 128) {
                int gr = m0 + tid;
                tokLds[tid] = (gr < cn) ? tokslot[e * T_TOK + gr] : 0;
            }
            __syncthreads();

            unsigned aOff[4];
#pragma unroll
            for (int c = 0; c < 4; c++) {
                int ar = m0 + c * 32 + wave * 8 + prow;
                if (ar >= cn) ar = cn - 1;
                aOff[c] = (unsigned)(offe + ar) * I_DIM;
            }
            const unsigned short* aBase = hbuf + lc8;
            const unsigned short* bBase =
                dbt + ((size_t)e * H_DIM + n0 + wave * 8 + prow) * I_DIM + lc8;
            unsigned short* ldsAW = ldsA + wave * 8 * 64;
            unsigned short* ldsBW = ldsB + wave * 8 * 64;

            const int wm = (wave & 1) * 64, wn = (wave >> 1) * 64;

            v4f acc[4][4];
#pragma unroll
            for (int i = 0; i < 4; i++)
#pragma unroll
                for (int j = 0; j < 4; j++) acc[i][j] = (v4f)0.f;

            for (int kb = 0; kb < I_DIM / 64; kb++) {
                const int k0 = kb * 64;
#pragma unroll
                for (int c = 0; c < 4; c++)
                    async16(aBase + aOff[c] + k0, ldsAW + c * 32 * 64);
#pragma unroll
                for (int c = 0; c < 4; c++)
                    async16(bBase + (size_t)c * 32 * I_DIM + k0, ldsBW + c * 32 * 64);
                __syncthreads();
#pragma unroll
                for (int ks = 0; ks < 2; ks++) {
                    const int pq = ((ks * 4 + quad) ^ (fm & 7)) * 8;
                    v8s aF[4], bF[4];
#pragma unroll
                    for (int im = 0; im < 4; im++)
                        aF[im] = *(const v8s*)&ldsA[(wm + im * 16 + fm) * 64 + pq];
#pragma unroll
                    for (int in = 0; in < 4; in++)
                        bF[in] = *(const v8s*)&ldsB[(wn + in * 16 + fm) * 64 + pq];
#pragma unroll
                    for (int im = 0; im < 4; im++)
#pragma unroll
                        for (int in = 0; in < 4; in++)
                            acc[im][in] = __builtin_amdgcn_mfma_f32_16x16x32_bf16(aF[im], bF[in], acc[im][in], 0, 0, 0);
                }
                __syncthreads();
            }

#pragma unroll
            for (int im = 0; im < 4; im++) {
#pragma unroll
                for (int reg = 0; reg < 4; reg++) {
                    int lr = wm + im * 16 + quad * 4 + reg;
                    int gr = m0 + lr;
                    if (gr < cn) {
                        int v = tokLds[lr];
                        int tok = v & 0xFFFF, s = (v >> 16) & 1;
#pragma unroll
                        for (int in = 0; in < 4; in++) {
                            int col = n0 + wn + in * 16 + fm;
                            ybuf[((size_t)s * T_TOK + tok) * H_DIM + col] = f2bf(acc[im][in][reg]);
                        }
                    }
                }
            }
        }
        __syncthreads();
        if (tid == 0)
            __hip_atomic_fetch_add(dncnt, 1, __ATOMIC_RELEASE, __HIP_MEMORY_SCOPE_AGENT);
    } else {
        // ---------------- combine item: 8192 output elems ----------------
        if (tid == 0) {
            while (__hip_atomic_load(dncnt, __ATOMIC_RELAXED, __HIP_MEMORY_SCOPE_AGENT) < NDN)
                __builtin_amdgcn_s_sleep(32);
        }
        __syncthreads();
        __builtin_amdgcn_fence(__ATOMIC_ACQUIRE, "agent");

        const size_t base = (size_t)item * 8192;
#pragma unroll
        for (int it = 0; it < 4; ++it) {
            const size_t i8 = base + (size_t)it * 2048 + tid * 8;
            const unsigned short* y0 = ybuf + i8;
            const unsigned short* y1 = ybuf + (size_t)T_TOK * H_DIM + i8;
            ushort4 a0 = *(const ushort4*)y0, a1 = *(const ushort4*)(y0 + 4);
            ushort4 b0 = *(const ushort4*)y1, b1 = *(const ushort4*)(y1 + 4);
            float4 o0, o1;
            o0.x = bf2f(a0.x) + bf2f(b0.x); o0.y = bf2f(a0.y) + bf2f(b0.y);
            o0.z = bf2f(a0.z) + bf2f(b0.z); o0.w = bf2f(a0.w) + bf2f(b0.w);
            o1.x = bf2f(a1.x) + bf2f(b1.x); o1.y = bf2f(a1.y) + bf2f(b1.y);
            o1.z = bf2f(a1.z) + bf2f(b1.z); o1.w = bf2f(a1.w) + bf2f(b1.w);
            *(float4*)(out + i8) = o0;
            *(float4*)(out + i8 + 4) = o1;
        }
    }
}

extern "C" void kernel_launch(void* const* d_in, const int* in_sizes, int n_in,
                              void* d_out, int out_size, void* d_ws, size_t ws_size,
                              hipStream_t stream) {
    const float* x  = (const float*)d_in[0];
    const float* rw = (const float*)d_in[1];
    const float* rb = (const float*)d_in[2];
    const float* gw = (const float*)d_in[3];
    const float* uw = (const float*)d_in[4];
    const float* dw = (const float*)d_in[5];
    float* out = (float*)d_out;

    char* ws = (char*)d_ws;
    size_t o = 0;
    auto alloc = [&](size_t bytes) { void* p = ws + o; o += (bytes + 255) & ~255ull; return p; };
    // meta: [0..4]=cnt  [5]=done  [6]=qhead  [7]=dncnt  [8..8+MAXTILE)=gucnt
    int*    meta    = (int*)   alloc((8 + MAXTILE) * 4);
    int*    tokslot = (int*)   alloc((size_t)N_EXP * T_TOK * 4);
    float*  pweight = (float*) alloc((size_t)N_EXP * T_TOK * 4);
    int*    top2e   = (int*)   alloc((size_t)T_TOK * 4);
    float2* top2w   = (float2*)alloc((size_t)T_TOK * 8);
    int4*   tiles   = (int4*)  alloc((size_t)MAXTILE * 16);
    unsigned short* xb   = (unsigned short*)alloc((size_t)T_TOK * H_DIM * 2);
    unsigned short* wbt  = (unsigned short*)alloc((size_t)N_EXP * 2 * I_DIM * H_DIM * 2);
    unsigned short* dbt  = (unsigned short*)alloc((size_t)N_EXP * H_DIM * I_DIM * 2);
    unsigned short* hbuf = (unsigned short*)alloc((size_t)(2 * T_TOK + 128) * I_DIM * 2);
    unsigned short* ybuf = (unsigned short*)alloc((size_t)2 * T_TOK * H_DIM * 2);

    hipMemsetAsync(meta, 0, (8 + MAXTILE) * 4, stream);

    dim3 pg(16, 16, 3 * N_EXP + 2);
    k_prep<<<pg, 256, 0, stream>>>(gw, uw, dw, wbt, dbt, x, rw, rb, xb, top2e, top2w);

    k_router_b<<<T_TOK / 256, 256, 0, stream>>>(top2e, top2w, meta, tokslot, pweight,
                                                meta + 5, tiles);

    k_mega<<<NGU + NDN + NCB, 256, 0, stream>>>(xb, wbt, dbt, tiles, tokslot, pweight,
                                                hbuf, ybuf, out,
                                                meta + 6, meta + 8, meta + 7);
}

// Round 5
// 278.638 us; speedup vs baseline: 1.9053x; 1.9053x over previous
//
#include <hip/hip_runtime.h>
#include <hip/hip_bf16.h>
#include <cstdint>
#include <cstddef>

#define T_TOK 8192
#define H_DIM 768
#define I_DIM 1024
#define N_EXP 5
#define MAXTILE 136
#define NRBLK 512   // router blocks in k_prep (2 z-planes x 256)

typedef short v8s __attribute__((ext_vector_type(8)));
typedef float v4f __attribute__((ext_vector_type(4)));

static __device__ __forceinline__ unsigned short f2bf(float f) {
    union { float f; unsigned int u; } v; v.f = f;
    unsigned int u = v.u;
    unsigned int r = (u + 0x7fffu + ((u >> 16) & 1u)) >> 16;
    return (unsigned short)r;
}
static __device__ __forceinline__ float bf2f(unsigned short s) {
    union { unsigned int u; float f; } v; v.u = ((unsigned int)s) << 16; return v.f;
}

// async 16B global->LDS (wave-uniform LDS base + lane*16)
static __device__ __forceinline__ void async16(const unsigned short* g, unsigned short* l) {
    __builtin_amdgcn_global_load_lds(
        (const __attribute__((address_space(1))) unsigned int*)g,
        (__attribute__((address_space(3))) unsigned int*)l, 16, 0, 0);
}

// ---- prep: 64x64-tile weight transposes (z<15) + router (z>=15) ----
// Router waves now ALSO do the expert-list insert (16 tokens/block) and the
// last-finishing router block builds the tile list (k_router_b eliminated).
__global__ void k_prep(const float* __restrict__ gw, const float* __restrict__ uw,
                       const float* __restrict__ dw,
                       unsigned short* __restrict__ wbt, unsigned short* __restrict__ dbt,
                       const float* __restrict__ x, const float* __restrict__ rw,
                       const float* __restrict__ rb, unsigned short* __restrict__ xb,
                       int* __restrict__ cnt, int* __restrict__ tokslot,
                       float* __restrict__ pweight, int* __restrict__ done,
                       int4* __restrict__ tiles) {
    const int z = blockIdx.z;
    const int tid = threadIdx.x;
    if (z < 3 * N_EXP) {
        __shared__ float tile[64][65];
        const int lrow = tid >> 4;
        const int lcol = (tid & 15) * 4;
        const int ocol = tid >> 2;
        const int seg = tid & 3;
        if (z < 2 * N_EXP) {
            if (blockIdx.y >= H_DIM / 64) return;
            const int e = z % N_EXP;
            const int isUp = z >= N_EXP;
            const float* src = (isUp ? uw : gw) + (size_t)e * H_DIM * I_DIM;
            const int c0 = blockIdx.x * 64, r0 = blockIdx.y * 64;
#pragma unroll
            for (int i = 0; i < 4; i++) {
                float4 v = *(const float4*)(src + (size_t)(r0 + i * 16 + lrow) * I_DIM + c0 + lcol);
                tile[i * 16 + lrow][lcol + 0] = v.x; tile[i * 16 + lrow][lcol + 1] = v.y;
                tile[i * 16 + lrow][lcol + 2] = v.z; tile[i * 16 + lrow][lcol + 3] = v.w;
            }
            __syncthreads();
            const int c = c0 + ocol;
            const int orow = (c >> 4) * 32 + (c & 15) + (isUp ? 16 : 0);
            unsigned short* dst = wbt + ((size_t)e * 2 * I_DIM + orow) * H_DIM + r0 + seg * 16;
#pragma unroll
            for (int q = 0; q < 4; q++) {
                ushort4 o;
                o.x = f2bf(tile[seg * 16 + q * 4 + 0][ocol]);
                o.y = f2bf(tile[seg * 16 + q * 4 + 1][ocol]);
                o.z = f2bf(tile[seg * 16 + q * 4 + 2][ocol]);
                o.w = f2bf(tile[seg * 16 + q * 4 + 3][ocol]);
                *(ushort4*)(dst + q * 4) = o;
            }
        } else {
            if (blockIdx.x >= H_DIM / 64) return;
            const int e = z - 2 * N_EXP;
            const float* src = dw + (size_t)e * I_DIM * H_DIM;
            unsigned short* dstb = dbt + (size_t)e * I_DIM * H_DIM;
            const int c0 = blockIdx.x * 64, r0 = blockIdx.y * 64;
#pragma unroll
            for (int i = 0; i < 4; i++) {
                float4 v = *(const float4*)(src + (size_t)(r0 + i * 16 + lrow) * H_DIM + c0 + lcol);
                tile[i * 16 + lrow][lcol + 0] = v.x; tile[i * 16 + lrow][lcol + 1] = v.y;
                tile[i * 16 + lrow][lcol + 2] = v.z; tile[i * 16 + lrow][lcol + 3] = v.w;
            }
            __syncthreads();
            const int c = c0 + ocol;
            unsigned short* dst = dstb + (size_t)c * I_DIM + r0 + seg * 16;
#pragma unroll
            for (int q = 0; q < 4; q++) {
                ushort4 o;
                o.x = f2bf(tile[seg * 16 + q * 4 + 0][ocol]);
                o.y = f2bf(tile[seg * 16 + q * 4 + 1][ocol]);
                o.z = f2bf(tile[seg * 16 + q * 4 + 2][ocol]);
                o.w = f2bf(tile[seg * 16 + q * 4 + 3][ocol]);
                *(ushort4*)(dst + q * 4) = o;
            }
        }
    } else {
        // router: 4 waves/block, 4 tokens/wave; fused list insert + tile build
        __shared__ int lcnt[N_EXP], lbase[N_EXP];
        const int wave = tid >> 6, lane = tid & 63;
        const int b = (z - 3 * N_EXP) * 256 + blockIdx.y * 16 + blockIdx.x;  // 0..511
        const int t0 = b * 16 + wave * 4;
        if (tid < N_EXP) lcnt[tid] = 0;
        float acc[4][N_EXP];
#pragma unroll
        for (int i = 0; i < 4; i++)
#pragma unroll
            for (int e = 0; e < N_EXP; e++) acc[i][e] = 0.f;
#pragma unroll
        for (int j = 0; j < H_DIM / 256; j++) {
            const int idx = j * 256 + lane * 4;
            float4 xv[4];
#pragma unroll
            for (int i = 0; i < 4; i++) {
                xv[i] = *(const float4*)(x + (size_t)(t0 + i) * H_DIM + idx);
                ushort4 o;
                o.x = f2bf(xv[i].x); o.y = f2bf(xv[i].y); o.z = f2bf(xv[i].z); o.w = f2bf(xv[i].w);
                *(ushort4*)(xb + (size_t)(t0 + i) * H_DIM + idx) = o;
            }
#pragma unroll
            for (int e = 0; e < N_EXP; e++) {
                float4 wv = *(const float4*)(rw + e * H_DIM + idx);
#pragma unroll
                for (int i = 0; i < 4; i++)
                    acc[i][e] += xv[i].x * wv.x + xv[i].y * wv.y + xv[i].z * wv.z + xv[i].w * wv.w;
            }
        }
#pragma unroll
        for (int s = 32; s > 0; s >>= 1) {
#pragma unroll
            for (int i = 0; i < 4; i++)
#pragma unroll
                for (int e = 0; e < N_EXP; e++) acc[i][e] += __shfl_down(acc[i][e], s);
        }
        __syncthreads();   // lcnt zeroed before lane0 shared atomics
        int se[8], sl[8], stok[8];
        float swt[8];
        if (lane == 0) {
#pragma unroll
            for (int i = 0; i < 4; i++) {
                float l[N_EXP];
#pragma unroll
                for (int e = 0; e < N_EXP; e++) l[e] = acc[i][e] + rb[e];
                int i1 = 0;
#pragma unroll
                for (int e = 1; e < N_EXP; e++) if (l[e] > l[i1]) i1 = e;
                int i2 = (i1 == 0) ? 1 : 0;
#pragma unroll
                for (int e = 0; e < N_EXP; e++) if (e != i1 && l[e] > l[i2]) i2 = e;
                float w1 = 1.f / (1.f + __expf(l[i2] - l[i1]));
                const int tok = t0 + i;
                se[2 * i] = i1; stok[2 * i] = tok; swt[2 * i] = w1;
                sl[2 * i] = atomicAdd(&lcnt[i1], 1);
                se[2 * i + 1] = i2; stok[2 * i + 1] = tok | (1 << 16); swt[2 * i + 1] = 1.f - w1;
                sl[2 * i + 1] = atomicAdd(&lcnt[i2], 1);
            }
        }
        __syncthreads();
        if (tid < N_EXP) lbase[tid] = atomicAdd(&cnt[tid], lcnt[tid]);
        __syncthreads();
        if (lane == 0) {
#pragma unroll
            for (int k = 0; k < 8; k++) {
                const int p = lbase[se[k]] + sl[k];
                tokslot[se[k] * T_TOK + p] = stok[k];
                pweight[se[k] * T_TOK + p] = swt[k];
            }
        }
        __syncthreads();
        if (tid == 0) {
            __threadfence();
            if (atomicAdd(done, 1) == NRBLK - 1) {
                int c[N_EXP], off = 0, idx = 0;
                for (int e = 0; e < N_EXP; e++) c[e] = atomicAdd(&cnt[e], 0);
                for (int e = 0; e < N_EXP; e++) {
                    for (int m0 = 0; m0 < c[e]; m0 += 128)
                        tiles[idx++] = make_int4(e, m0, off, c[e]);
                    off += c[e];
                }
                for (; idx < MAXTILE; idx++) tiles[idx] = make_int4(-1, 0, 0, 0);
            }
        }
    }
}

// ---- gate+up fused GEMM: BK=64, XOR-swizzled LDS, 32KB LDS -> 5 blocks/CU ----
__launch_bounds__(256, 5)
__global__ void k_gateup(const unsigned short* __restrict__ xb,
                         const unsigned short* __restrict__ wbt,
                         const int4* __restrict__ tiles,
                         const int* __restrict__ tokslot,
                         const float* __restrict__ pweight,
                         unsigned short* __restrict__ hbuf) {
    const int4 td = tiles[blockIdx.x];
    const int e = td.x;
    if (e < 0) return;
    const int m0 = td.y, offe = td.z, cn = td.w;
    const int n0 = blockIdx.y * 64;

    __shared__ __align__(16) unsigned short ldsA[128 * 64];
    __shared__ __align__(16) unsigned short ldsB[128 * 64];

    const int tid = threadIdx.x;
    const int lane = tid & 63;
    const int wave = tid >> 6;
    const int fm = lane & 15, quad = lane >> 4;

    const int prow = lane >> 3;          // 0..7
    const int pc = lane & 7;             // physical chunk
    const int lc8 = (pc ^ prow) * 8;     // logical chunk offset in shorts

    unsigned aOff[4];
#pragma unroll
    for (int c = 0; c < 4; c++) {
        const int gr = m0 + c * 32 + wave * 8 + prow;
        const int tk = (gr < cn) ? (tokslot[e * T_TOK + gr] & 0xFFFF) : 0;
        aOff[c] = (unsigned)tk * H_DIM;
    }
    const unsigned short* aBase = xb + lc8;
    const unsigned short* bBase =
        wbt + ((size_t)e * 2 * I_DIM + n0 * 2 + wave * 8 + prow) * H_DIM + lc8;
    unsigned short* ldsAW = ldsA + wave * 8 * 64;   // + c*32*64
    unsigned short* ldsBW = ldsB + wave * 8 * 64;

    const int wm = (wave & 1) * 64, wnw = wave >> 1;

    v4f acc[4][4];
#pragma unroll
    for (int i = 0; i < 4; i++)
#pragma unroll
        for (int j = 0; j < 4; j++) acc[i][j] = (v4f)0.f;

    for (int kb = 0; kb < H_DIM / 64; kb++) {   // 12 iters
        const int k0 = kb * 64;
#pragma unroll
        for (int c = 0; c < 4; c++)
            async16(aBase + aOff[c] + k0, ldsAW + c * 32 * 64);
#pragma unroll
        for (int c = 0; c < 4; c++)
            async16(bBase + (size_t)c * 32 * H_DIM + k0, ldsBW + c * 32 * 64);
        __syncthreads();
#pragma unroll
        for (int ks = 0; ks < 2; ks++) {
            const int pq = ((ks * 4 + quad) ^ (fm & 7)) * 8;
            v8s aF[4], bF[4];
#pragma unroll
            for (int im = 0; im < 4; im++)
                aF[im] = *(const v8s*)&ldsA[(wm + im * 16 + fm) * 64 + pq];
#pragma unroll
            for (int in = 0; in < 4; in++)
                bF[in] = *(const v8s*)&ldsB[(wnw * 64 + in * 16 + fm) * 64 + pq];
#pragma unroll
            for (int im = 0; im < 4; im++)
#pragma unroll
                for (int in = 0; in < 4; in++)
                    acc[im][in] = __builtin_amdgcn_mfma_f32_16x16x32_bf16(aF[im], bF[in], acc[im][in], 0, 0, 0);
        }
        __syncthreads();
    }

    // acc[im][2j]=gate, acc[im][2j+1]=up, cols n0 + wnw*32 + j*16 + fm
#pragma unroll
    for (int im = 0; im < 4; im++) {
#pragma unroll
        for (int reg = 0; reg < 4; reg++) {
            int lr = wm + im * 16 + quad * 4 + reg;
            int gr = m0 + lr;
            if (gr < cn) {
                float pw = pweight[e * T_TOK + gr];
                size_t base = (size_t)(offe + gr) * I_DIM + n0 + wnw * 32 + fm;
#pragma unroll
                for (int j = 0; j < 2; j++) {
                    float g = acc[im][2 * j][reg];
                    float u = acc[im][2 * j + 1][reg];
                    float s = g / (1.f + __expf(-g));
                    hbuf[base + j * 16] = f2bf(s * u * pw);
                }
            }
        }
    }
}

// ---- down GEMM: BK=64, XOR-swizzled, 32KB LDS -> 5 blocks/CU ----
__launch_bounds__(256, 5)
__global__ void k_down(const unsigned short* __restrict__ hbuf,
                       const unsigned short* __restrict__ dbt,
                       const int4* __restrict__ tiles,
                       const int* __restrict__ tokslot,
                       unsigned short* __restrict__ ybuf) {
    const int4 td = tiles[blockIdx.x];
    const int e = td.x;
    if (e < 0) return;
    const int m0 = td.y, offe = td.z, cn = td.w;
    const int n0 = blockIdx.y * 128;

    __shared__ __align__(16) unsigned short ldsA[128 * 64];
    __shared__ __align__(16) unsigned short ldsB[128 * 64];

    const int tid = threadIdx.x;
    const int lane = tid & 63;
    const int wave = tid >> 6;
    const int fm = lane & 15, quad = lane >> 4;

    const int prow = lane >> 3;
    const int pc = lane & 7;
    const int lc8 = (pc ^ prow) * 8;

    unsigned aOff[4];
#pragma unroll
    for (int c = 0; c < 4; c++) {
        int ar = m0 + c * 32 + wave * 8 + prow;
        if (ar >= cn) ar = cn - 1;
        aOff[c] = (unsigned)(offe + ar) * I_DIM;
    }
    const unsigned short* aBase = hbuf + lc8;
    const unsigned short* bBase =
        dbt + ((size_t)e * H_DIM + n0 + wave * 8 + prow) * I_DIM + lc8;
    unsigned short* ldsAW = ldsA + wave * 8 * 64;
    unsigned short* ldsBW = ldsB + wave * 8 * 64;

    const int wm = (wave & 1) * 64, wn = (wave >> 1) * 64;

    v4f acc[4][4];
#pragma unroll
    for (int i = 0; i < 4; i++)
#pragma unroll
        for (int j = 0; j < 4; j++) acc[i][j] = (v4f)0.f;

    for (int kb = 0; kb < I_DIM / 64; kb++) {   // 16 iters
        const int k0 = kb * 64;
#pragma unroll
        for (int c = 0; c < 4; c++)
            async16(aBase + aOff[c] + k0, ldsAW + c * 32 * 64);
#pragma unroll
        for (int c = 0; c < 4; c++)
            async16(bBase + (size_t)c * 32 * I_DIM + k0, ldsBW + c * 32 * 64);
        __syncthreads();
#pragma unroll
        for (int ks = 0; ks < 2; ks++) {
            const int pq = ((ks * 4 + quad) ^ (fm & 7)) * 8;
            v8s aF[4], bF[4];
#pragma unroll
            for (int im = 0; im < 4; im++)
                aF[im] = *(const v8s*)&ldsA[(wm + im * 16 + fm) * 64 + pq];
#pragma unroll
            for (int in = 0; in < 4; in++)
                bF[in] = *(const v8s*)&ldsB[(wn + in * 16 + fm) * 64 + pq];
#pragma unroll
            for (int im = 0; im < 4; im++)
#pragma unroll
                for (int in = 0; in < 4; in++)
                    acc[im][in] = __builtin_amdgcn_mfma_f32_16x16x32_bf16(aF[im], bF[in], acc[im][in], 0, 0, 0);
        }
        __syncthreads();
    }

#pragma unroll
    for (int im = 0; im < 4; im++) {
#pragma unroll
        for (int reg = 0; reg < 4; reg++) {
            int lr = wm + im * 16 + quad * 4 + reg;
            int gr = m0 + lr;
            if (gr < cn) {
                int v = tokslot[e * T_TOK + gr];
                int tok = v & 0xFFFF, s = (v >> 16) & 1;
#pragma unroll
                for (int in = 0; in < 4; in++) {
                    int col = n0 + wn + in * 16 + fm;
                    ybuf[((size_t)s * T_TOK + tok) * H_DIM + col] = f2bf(acc[im][in][reg]);
                }
            }
        }
    }
}

// ---- combine: out = ybuf[0] + ybuf[1], fp32 out ----
__global__ void k_combine(const unsigned short* __restrict__ ybuf, float* __restrict__ out) {
    const size_t i8 = ((size_t)blockIdx.x * 256 + threadIdx.x) * 8;
    const unsigned short* y0 = ybuf + i8;
    const unsigned short* y1 = ybuf + (size_t)T_TOK * H_DIM + i8;
    ushort4 a0 = *(const ushort4*)y0, a1 = *(const ushort4*)(y0 + 4);
    ushort4 b0 = *(const ushort4*)y1, b1 = *(const ushort4*)(y1 + 4);
    float4 o0, o1;
    o0.x = bf2f(a0.x) + bf2f(b0.x); o0.y = bf2f(a0.y) + bf2f(b0.y);
    o0.z = bf2f(a0.z) + bf2f(b0.z); o0.w = bf2f(a0.w) + bf2f(b0.w);
    o1.x = bf2f(a1.x) + bf2f(b1.x); o1.y = bf2f(a1.y) + bf2f(b1.y);
    o1.z = bf2f(a1.z) + bf2f(b1.z); o1.w = bf2f(a1.w) + bf2f(b1.w);
    *(float4*)(out + i8) = o0;
    *(float4*)(out + i8 + 4) = o1;
}

extern "C" void kernel_launch(void* const* d_in, const int* in_sizes, int n_in,
                              void* d_out, int out_size, void* d_ws, size_t ws_size,
                              hipStream_t stream) {
    const float* x  = (const float*)d_in[0];
    const float* rw = (const float*)d_in[1];
    const float* rb = (const float*)d_in[2];
    const float* gw = (const float*)d_in[3];
    const float* uw = (const float*)d_in[4];
    const float* dw = (const float*)d_in[5];
    float* out = (float*)d_out;

    char* ws = (char*)d_ws;
    size_t o = 0;
    auto alloc = [&](size_t bytes) { void* p = ws + o; o += (bytes + 255) & ~255ull; return p; };
    int*    cnt     = (int*)   alloc(8 * 4);              // cnt[5] + done counter
    int*    tokslot = (int*)   alloc((size_t)N_EXP * T_TOK * 4);
    float*  pweight = (float*) alloc((size_t)N_EXP * T_TOK * 4);
    int4*   tiles   = (int4*)  alloc((size_t)MAXTILE * 16);
    unsigned short* xb   = (unsigned short*)alloc((size_t)T_TOK * H_DIM * 2);
    unsigned short* wbt  = (unsigned short*)alloc((size_t)N_EXP * 2 * I_DIM * H_DIM * 2);
    unsigned short* dbt  = (unsigned short*)alloc((size_t)N_EXP * H_DIM * I_DIM * 2);
    unsigned short* hbuf = (unsigned short*)alloc((size_t)(2 * T_TOK + 128) * I_DIM * 2);
    unsigned short* ybuf = (unsigned short*)alloc((size_t)2 * T_TOK * H_DIM * 2);

    hipMemsetAsync(cnt, 0, 8 * 4, stream);

    // z<15: 64x64 weight transposes; z in {15,16}: router + list insert + tile build
    dim3 pg(16, 16, 3 * N_EXP + 2);
    k_prep<<<pg, 256, 0, stream>>>(gw, uw, dw, wbt, dbt, x, rw, rb, xb,
                                   cnt, tokslot, pweight, cnt + 5, tiles);

    dim3 g1(MAXTILE, I_DIM / 64);
    k_gateup<<<g1, 256, 0, stream>>>(xb, wbt, tiles, tokslot, pweight, hbuf);

    dim3 g2(MAXTILE, H_DIM / 128);
    k_down<<<g2, 256, 0, stream>>>(hbuf, dbt, tiles, tokslot, ybuf);

    k_combine<<<(T_TOK * H_DIM) / (256 * 8), 256, 0, stream>>>(ybuf, out);
}

// Round 6
// 235.041 us; speedup vs baseline: 2.2587x; 1.1855x over previous
//
#include <hip/hip_runtime.h>
#include <hip/hip_bf16.h>
#include <cstdint>
#include <cstddef>

#define T_TOK 8192
#define H_DIM 768
#define I_DIM 1024
#define N_EXP 5
#define MAXTILE 136

typedef short v8s __attribute__((ext_vector_type(8)));
typedef float v4f __attribute__((ext_vector_type(4)));

static __device__ __forceinline__ unsigned short f2bf(float f) {
    union { float f; unsigned int u; } v; v.f = f;
    unsigned int u = v.u;
    unsigned int r = (u + 0x7fffu + ((u >> 16) & 1u)) >> 16;
    return (unsigned short)r;
}
static __device__ __forceinline__ float bf2f(unsigned short s) {
    union { unsigned int u; float f; } v; v.u = ((unsigned int)s) << 16; return v.f;
}

// async 16B global->LDS (wave-uniform LDS base + lane*16)
static __device__ __forceinline__ void async16(const unsigned short* g, unsigned short* l) {
    __builtin_amdgcn_global_load_lds(
        (const __attribute__((address_space(1))) unsigned int*)g,
        (__attribute__((address_space(3))) unsigned int*)l, 16, 0, 0);
}

// ---- prep: weight transposes (z<15) + router logits/top2 + x->bf16 (z>=15) ----
__global__ void k_prep(const float* __restrict__ gw, const float* __restrict__ uw,
                       const float* __restrict__ dw,
                       unsigned short* __restrict__ wbt, unsigned short* __restrict__ dbt,
                       const float* __restrict__ x, const float* __restrict__ rw,
                       const float* __restrict__ rb, unsigned short* __restrict__ xb,
                       int* __restrict__ top2e, float2* __restrict__ top2w) {
    const int z = blockIdx.z;
    const int tid = threadIdx.x;
    if (z < 3 * N_EXP) {
        __shared__ float tile[32][33];
        const int row = tid >> 3, cq = tid & 7;
        const int ocol = tid >> 3, seg = tid & 7;
        if (z < 2 * N_EXP) {
            if (blockIdx.y >= H_DIM / 32) return;
            const int e = z % N_EXP;
            const int isUp = z >= N_EXP;
            const float* src = (isUp ? uw : gw) + (size_t)e * H_DIM * I_DIM;
            const int c0 = blockIdx.x * 32, r0 = blockIdx.y * 32;
            float4 v = *(const float4*)(src + (size_t)(r0 + row) * I_DIM + c0 + cq * 4);
            tile[row][cq * 4 + 0] = v.x; tile[row][cq * 4 + 1] = v.y;
            tile[row][cq * 4 + 2] = v.z; tile[row][cq * 4 + 3] = v.w;
            __syncthreads();
            int c = c0 + ocol;
            int orow = (c >> 4) * 32 + (c & 15) + (isUp ? 16 : 0);
            ushort4 o;
            o.x = f2bf(tile[seg * 4 + 0][ocol]); o.y = f2bf(tile[seg * 4 + 1][ocol]);
            o.z = f2bf(tile[seg * 4 + 2][ocol]); o.w = f2bf(tile[seg * 4 + 3][ocol]);
            *(ushort4*)(wbt + ((size_t)e * 2 * I_DIM + orow) * H_DIM + r0 + seg * 4) = o;
        } else {
            if (blockIdx.x >= H_DIM / 32) return;
            const int e = z - 2 * N_EXP;
            const float* src = dw + (size_t)e * I_DIM * H_DIM;
            unsigned short* dst = dbt + (size_t)e * I_DIM * H_DIM;
            const int c0 = blockIdx.x * 32, r0 = blockIdx.y * 32;
            float4 v = *(const float4*)(src + (size_t)(r0 + row) * H_DIM + c0 + cq * 4);
            tile[row][cq * 4 + 0] = v.x; tile[row][cq * 4 + 1] = v.y;
            tile[row][cq * 4 + 2] = v.z; tile[row][cq * 4 + 3] = v.w;
            __syncthreads();
            ushort4 o;
            o.x = f2bf(tile[seg * 4 + 0][ocol]); o.y = f2bf(tile[seg * 4 + 1][ocol]);
            o.z = f2bf(tile[seg * 4 + 2][ocol]); o.w = f2bf(tile[seg * 4 + 3][ocol]);
            *(ushort4*)(dst + (size_t)(c0 + ocol) * I_DIM + r0 + seg * 4) = o;
        }
    } else {
        const int wave = tid >> 6, lane = tid & 63;
        const int t = (((z - 3 * N_EXP) * 1024 + blockIdx.y * 32 + blockIdx.x) * 4) + wave;
        const float* xr = x + (size_t)t * H_DIM;
        unsigned short* xbr = xb + (size_t)t * H_DIM;
        float acc[N_EXP];
#pragma unroll
        for (int e = 0; e < N_EXP; e++) acc[e] = 0.f;
#pragma unroll
        for (int j = 0; j < H_DIM / 256; j++) {
            int idx = j * 256 + lane * 4;
            float4 xv = *(const float4*)(xr + idx);
            ushort4 o;
            o.x = f2bf(xv.x); o.y = f2bf(xv.y); o.z = f2bf(xv.z); o.w = f2bf(xv.w);
            *(ushort4*)(xbr + idx) = o;
#pragma unroll
            for (int e = 0; e < N_EXP; e++) {
                float4 wv = *(const float4*)(rw + e * H_DIM + idx);
                acc[e] += xv.x * wv.x + xv.y * wv.y + xv.z * wv.z + xv.w * wv.w;
            }
        }
#pragma unroll
        for (int s = 32; s > 0; s >>= 1) {
#pragma unroll
            for (int e = 0; e < N_EXP; e++) acc[e] += __shfl_down(acc[e], s);
        }
        if (lane == 0) {
            float l[N_EXP];
#pragma unroll
            for (int e = 0; e < N_EXP; e++) l[e] = acc[e] + rb[e];
            int i1 = 0;
#pragma unroll
            for (int e = 1; e < N_EXP; e++) if (l[e] > l[i1]) i1 = e;
            int i2 = (i1 == 0) ? 1 : 0;
#pragma unroll
            for (int e = 0; e < N_EXP; e++) if (e != i1 && l[e] > l[i2]) i2 = e;
            float w1 = 1.f / (1.f + __expf(l[i2] - l[i1]));
            top2e[t] = i1 | (i2 << 8);
            top2w[t] = make_float2(w1, 1.f - w1);
        }
    }
}

// ---- router phase B: list build + (last block) tile-list build ----
__global__ void k_router_b(const int* __restrict__ top2e, const float2* __restrict__ top2w,
                           int* __restrict__ cnt, int* __restrict__ tokslot,
                           float* __restrict__ pweight, int* __restrict__ done,
                           int4* __restrict__ tiles) {
    __shared__ int lcnt[N_EXP], lbase[N_EXP];
    const int tid = threadIdx.x;
    if (tid < N_EXP) lcnt[tid] = 0;
    __syncthreads();
    const int t = blockIdx.x * 256 + tid;
    const int pe = top2e[t];
    const float2 wv = top2w[t];
    const int e1 = pe & 0xff, e2 = pe >> 8;
    const int s1 = atomicAdd(&lcnt[e1], 1);
    const int s2 = atomicAdd(&lcnt[e2], 1);
    __syncthreads();
    if (tid < N_EXP) lbase[tid] = atomicAdd(&cnt[tid], lcnt[tid]);
    __syncthreads();
    const int p1 = lbase[e1] + s1;
    tokslot[e1 * T_TOK + p1] = t; pweight[e1 * T_TOK + p1] = wv.x;
    const int p2 = lbase[e2] + s2;
    tokslot[e2 * T_TOK + p2] = t | (1 << 16); pweight[e2 * T_TOK + p2] = wv.y;
    __syncthreads();
    if (tid == 0) {
        __threadfence();
        if (atomicAdd(done, 1) == (int)gridDim.x - 1) {
            int c[N_EXP], off = 0, idx = 0;
            for (int e = 0; e < N_EXP; e++) c[e] = atomicAdd(&cnt[e], 0);
            for (int e = 0; e < N_EXP; e++) {
                for (int m0 = 0; m0 < c[e]; m0 += 128)
                    tiles[idx++] = make_int4(e, m0, off, c[e]);
                off += c[e];
            }
            for (; idx < MAXTILE; idx++) tiles[idx] = make_int4(-1, 0, 0, 0);
        }
    }
}

// ---- gate+up fused GEMM: BK=64, XOR-swizzled LDS; exactly 32 KiB LDS ----
// (5 blocks/CU via LDS limit; launch_bounds kept at 4 so regalloc stays loose)
__launch_bounds__(256, 4)
__global__ void k_gateup(const unsigned short* __restrict__ xb,
                         const unsigned short* __restrict__ wbt,
                         const int4* __restrict__ tiles,
                         const int* __restrict__ tokslot,
                         const float* __restrict__ pweight,
                         unsigned short* __restrict__ hbuf) {
    const int4 td = tiles[blockIdx.x];
    const int e = td.x;
    if (e < 0) return;
    const int m0 = td.y, offe = td.z, cn = td.w;
    const int n0 = blockIdx.y * 64;

    __shared__ __align__(16) unsigned short ldsA[128 * 64];
    __shared__ __align__(16) unsigned short ldsB[128 * 64];

    const int tid = threadIdx.x;
    const int lane = tid & 63;
    const int wave = tid >> 6;
    const int fm = lane & 15, quad = lane >> 4;

    // staging geometry: per call a wave covers 8 rows x 8 chunks
    const int prow = lane >> 3;          // 0..7
    const int pc = lane & 7;             // physical chunk
    const int lc8 = (pc ^ prow) * 8;     // logical chunk offset in shorts

    unsigned aOff[4];
#pragma unroll
    for (int c = 0; c < 4; c++) {
        const int gr = m0 + c * 32 + wave * 8 + prow;
        const int tk = (gr < cn) ? (tokslot[e * T_TOK + gr] & 0xFFFF) : 0;
        aOff[c] = (unsigned)tk * H_DIM;
    }
    const unsigned short* aBase = xb + lc8;
    const unsigned short* bBase =
        wbt + ((size_t)e * 2 * I_DIM + n0 * 2 + wave * 8 + prow) * H_DIM + lc8;
    unsigned short* ldsAW = ldsA + wave * 8 * 64;   // + c*32*64
    unsigned short* ldsBW = ldsB + wave * 8 * 64;

    const int wm = (wave & 1) * 64, wnw = wave >> 1;

    v4f acc[4][4];
#pragma unroll
    for (int i = 0; i < 4; i++)
#pragma unroll
        for (int j = 0; j < 4; j++) acc[i][j] = (v4f)0.f;

    for (int kb = 0; kb < H_DIM / 64; kb++) {   // 12 iters
        const int k0 = kb * 64;
#pragma unroll
        for (int c = 0; c < 4; c++)
            async16(aBase + aOff[c] + k0, ldsAW + c * 32 * 64);
#pragma unroll
        for (int c = 0; c < 4; c++)
            async16(bBase + (size_t)c * 32 * H_DIM + k0, ldsBW + c * 32 * 64);
        __syncthreads();
#pragma unroll
        for (int ks = 0; ks < 2; ks++) {
            const int pq = ((ks * 4 + quad) ^ (fm & 7)) * 8;
            v8s aF[4], bF[4];
#pragma unroll
            for (int im = 0; im < 4; im++)
                aF[im] = *(const v8s*)&ldsA[(wm + im * 16 + fm) * 64 + pq];
#pragma unroll
            for (int in = 0; in < 4; in++)
                bF[in] = *(const v8s*)&ldsB[(wnw * 64 + in * 16 + fm) * 64 + pq];
#pragma unroll
            for (int im = 0; im < 4; im++)
#pragma unroll
                for (int in = 0; in < 4; in++)
                    acc[im][in] = __builtin_amdgcn_mfma_f32_16x16x32_bf16(aF[im], bF[in], acc[im][in], 0, 0, 0);
        }
        __syncthreads();
    }

    // acc[im][2j]=gate, acc[im][2j+1]=up, cols n0 + wnw*32 + j*16 + fm
    // pw via aligned float4 (pweight padded by launcher so +3 never exits buffer)
#pragma unroll
    for (int im = 0; im < 4; im++) {
        const int lr0 = wm + im * 16 + quad * 4;
        const float4 pw4 = *(const float4*)(pweight + e * T_TOK + m0 + lr0);
#pragma unroll
        for (int reg = 0; reg < 4; reg++) {
            int gr = m0 + lr0 + reg;
            if (gr < cn) {
                float pw = (&pw4.x)[reg];
                size_t base = (size_t)(offe + gr) * I_DIM + n0 + wnw * 32 + fm;
#pragma unroll
                for (int j = 0; j < 2; j++) {
                    float g = acc[im][2 * j][reg];
                    float u = acc[im][2 * j + 1][reg];
                    float s = g / (1.f + __expf(-g));
                    hbuf[base + j * 16] = f2bf(s * u * pw);
                }
            }
        }
    }
}

// ---- down GEMM: BK=64, XOR-swizzled; exactly 32 KiB LDS ----
__launch_bounds__(256, 4)
__global__ void k_down(const unsigned short* __restrict__ hbuf,
                       const unsigned short* __restrict__ dbt,
                       const int4* __restrict__ tiles,
                       const int* __restrict__ tokslot,
                       unsigned short* __restrict__ ybuf) {
    const int4 td = tiles[blockIdx.x];
    const int e = td.x;
    if (e < 0) return;
    const int m0 = td.y, offe = td.z, cn = td.w;
    const int n0 = blockIdx.y * 128;

    __shared__ __align__(16) unsigned short ldsA[128 * 64];
    __shared__ __align__(16) unsigned short ldsB[128 * 64];

    const int tid = threadIdx.x;
    const int lane = tid & 63;
    const int wave = tid >> 6;
    const int fm = lane & 15, quad = lane >> 4;

    const int prow = lane >> 3;
    const int pc = lane & 7;
    const int lc8 = (pc ^ prow) * 8;

    unsigned aOff[4];
#pragma unroll
    for (int c = 0; c < 4; c++) {
        int ar = m0 + c * 32 + wave * 8 + prow;
        if (ar >= cn) ar = cn - 1;
        aOff[c] = (unsigned)(offe + ar) * I_DIM;
    }
    const unsigned short* aBase = hbuf + lc8;
    const unsigned short* bBase =
        dbt + ((size_t)e * H_DIM + n0 + wave * 8 + prow) * I_DIM + lc8;
    unsigned short* ldsAW = ldsA + wave * 8 * 64;
    unsigned short* ldsBW = ldsB + wave * 8 * 64;

    const int wm = (wave & 1) * 64, wn = (wave >> 1) * 64;

    v4f acc[4][4];
#pragma unroll
    for (int i = 0; i < 4; i++)
#pragma unroll
        for (int j = 0; j < 4; j++) acc[i][j] = (v4f)0.f;

    for (int kb = 0; kb < I_DIM / 64; kb++) {   // 16 iters
        const int k0 = kb * 64;
#pragma unroll
        for (int c = 0; c < 4; c++)
            async16(aBase + aOff[c] + k0, ldsAW + c * 32 * 64);
#pragma unroll
        for (int c = 0; c < 4; c++)
            async16(bBase + (size_t)c * 32 * I_DIM + k0, ldsBW + c * 32 * 64);
        __syncthreads();
#pragma unroll
        for (int ks = 0; ks < 2; ks++) {
            const int pq = ((ks * 4 + quad) ^ (fm & 7)) * 8;
            v8s aF[4], bF[4];
#pragma unroll
            for (int im = 0; im < 4; im++)
                aF[im] = *(const v8s*)&ldsA[(wm + im * 16 + fm) * 64 + pq];
#pragma unroll
            for (int in = 0; in < 4; in++)
                bF[in] = *(const v8s*)&ldsB[(wn + in * 16 + fm) * 64 + pq];
#pragma unroll
            for (int im = 0; im < 4; im++)
#pragma unroll
                for (int in = 0; in < 4; in++)
                    acc[im][in] = __builtin_amdgcn_mfma_f32_16x16x32_bf16(aF[im], bF[in], acc[im][in], 0, 0, 0);
        }
        __syncthreads();
    }

    // tok via aligned int4 (tokslot padded by launcher)
#pragma unroll
    for (int im = 0; im < 4; im++) {
        const int lr0 = wm + im * 16 + quad * 4;
        const int4 tv4 = *(const int4*)(tokslot + e * T_TOK + m0 + lr0);
#pragma unroll
        for (int reg = 0; reg < 4; reg++) {
            int gr = m0 + lr0 + reg;
            if (gr < cn) {
                int v = (&tv4.x)[reg];
                int tok = v & 0xFFFF, s = (v >> 16) & 1;
#pragma unroll
                for (int in = 0; in < 4; in++) {
                    int col = n0 + wn + in * 16 + fm;
                    ybuf[((size_t)s * T_TOK + tok) * H_DIM + col] = f2bf(acc[im][in][reg]);
                }
            }
        }
    }
}

// ---- combine: out = ybuf[0] + ybuf[1], fp32 out ----
__global__ void k_combine(const unsigned short* __restrict__ ybuf, float* __restrict__ out) {
    const size_t i8 = ((size_t)blockIdx.x * 256 + threadIdx.x) * 8;
    const unsigned short* y0 = ybuf + i8;
    const unsigned short* y1 = ybuf + (size_t)T_TOK * H_DIM + i8;
    ushort4 a0 = *(const ushort4*)y0, a1 = *(const ushort4*)(y0 + 4);
    ushort4 b0 = *(const ushort4*)y1, b1 = *(const ushort4*)(y1 + 4);
    float4 o0, o1;
    o0.x = bf2f(a0.x) + bf2f(b0.x); o0.y = bf2f(a0.y) + bf2f(b0.y);
    o0.z = bf2f(a0.z) + bf2f(b0.z); o0.w = bf2f(a0.w) + bf2f(b0.w);
    o1.x = bf2f(a1.x) + bf2f(b1.x); o1.y = bf2f(a1.y) + bf2f(b1.y);
    o1.z = bf2f(a1.z) + bf2f(b1.z); o1.w = bf2f(a1.w) + bf2f(b1.w);
    *(float4*)(out + i8) = o0;
    *(float4*)(out + i8 + 4) = o1;
}

extern "C" void kernel_launch(void* const* d_in, const int* in_sizes, int n_in,
                              void* d_out, int out_size, void* d_ws, size_t ws_size,
                              hipStream_t stream) {
    const float* x  = (const float*)d_in[0];
    const float* rw = (const float*)d_in[1];
    const float* rb = (const float*)d_in[2];
    const float* gw = (const float*)d_in[3];
    const float* uw = (const float*)d_in[4];
    const float* dw = (const float*)d_in[5];
    float* out = (float*)d_out;

    char* ws = (char*)d_ws;
    size_t o = 0;
    auto alloc = [&](size_t bytes) { void* p = ws + o; o += (bytes + 255) & ~255ull; return p; };
    int*    cnt     = (int*)   alloc(8 * 4);              // cnt[5] + done counter
    int*    tokslot = (int*)   alloc((size_t)N_EXP * T_TOK * 4 + 512);   // +pad for int4 tail
    float*  pweight = (float*) alloc((size_t)N_EXP * T_TOK * 4 + 512);   // +pad for float4 tail
    int*    top2e   = (int*)   alloc((size_t)T_TOK * 4);
    float2* top2w   = (float2*)alloc((size_t)T_TOK * 8);
    int4*   tiles   = (int4*)  alloc((size_t)MAXTILE * 16);
    unsigned short* xb   = (unsigned short*)alloc((size_t)T_TOK * H_DIM * 2);
    unsigned short* wbt  = (unsigned short*)alloc((size_t)N_EXP * 2 * I_DIM * H_DIM * 2);
    unsigned short* dbt  = (unsigned short*)alloc((size_t)N_EXP * H_DIM * I_DIM * 2);
    unsigned short* hbuf = (unsigned short*)alloc((size_t)(2 * T_TOK + 128) * I_DIM * 2);
    unsigned short* ybuf = (unsigned short*)alloc((size_t)2 * T_TOK * H_DIM * 2);

    hipMemsetAsync(cnt, 0, 8 * 4, stream);

    // z<15: weight transposes; z in {15,16}: router logits/top2 + x->bf16
    dim3 pg(I_DIM / 32, I_DIM / 32, 3 * N_EXP + 2);
    k_prep<<<pg, 256, 0, stream>>>(gw, uw, dw, wbt, dbt, x, rw, rb, xb, top2e, top2w);

    k_router_b<<<T_TOK / 256, 256, 0, stream>>>(top2e, top2w, cnt, tokslot, pweight,
                                                cnt + 5, tiles);

    dim3 g1(MAXTILE, I_DIM / 64);
    k_gateup<<<g1, 256, 0, stream>>>(xb, wbt, tiles, tokslot, pweight, hbuf);

    dim3 g2(MAXTILE, H_DIM / 128);
    k_down<<<g2, 256, 0, stream>>>(hbuf, dbt, tiles, tokslot, ybuf);

    k_combine<<<(T_TOK * H_DIM) / (256 * 8), 256, 0, stream>>>(ybuf, out);
}